// Round 5
// baseline (6274.582 us; speedup 1.0000x reference)
//
#include <hip/hip_runtime.h>
#include <stdint.h>
#include <stddef.h>

#define T_STEPS 1024
#define BATCH   512
#define HID     256
#define DIN     64

typedef __attribute__((ext_vector_type(8))) short short8;
typedef __attribute__((ext_vector_type(4))) short short4v;
typedef __attribute__((ext_vector_type(2))) short short2v;
typedef __attribute__((ext_vector_type(4))) float float4v;

static __device__ __forceinline__ short f2bf(float f) {
  union { float f; unsigned u; } v; v.f = f;
  unsigned r = (v.u + 0x7FFFu + ((v.u >> 16) & 1u)) >> 16;
  return (short)r;
}
static __device__ __forceinline__ float sigm(float x) {
  return 1.0f / (1.0f + __expf(-x));
}
static __device__ __forceinline__ float tanh_f(float x) {
  return 2.0f / (1.0f + __expf(-2.0f * x)) - 1.0f;
}

// ---------------------------------------------------------------------------
// Split-phase MALL atomic read: issue early (loop start), wait+check late.
// The returning atomic is the only L1-proof read (R2 lesson); issuing it
// ~1000cy before the check hides the full MALL RTT under MFMA phases.
// ---------------------------------------------------------------------------
static __device__ __forceinline__ void apoll_issue(const unsigned long long* p,
                                                   unsigned long long& r0,
                                                   unsigned long long& r1) {
  unsigned long long z = 0;
  asm volatile("global_atomic_add_x2 %0, %2, %3, off sc0\n\t"
               "global_atomic_add_x2 %1, %2, %3, off offset:8 sc0"
               : "=&v"(r0), "=&v"(r1)
               : "v"(p), "v"(z)
               : "memory");
}
static __device__ __forceinline__ void apoll_wait(unsigned long long& r0,
                                                  unsigned long long& r1) {
  asm volatile("s_waitcnt vmcnt(0)" : "+v"(r0), "+v"(r1) :: "memory");
}

// ---------------------------------------------------------------------------
// Persistent LSTM recurrence, 2-WAY STREAM-INTERLEAVED (this round's change).
// 32 blocks = 16 pair-indices x 2 gate-halves; partner = blk ^ 16.
// Each block runs TWO batch-groups (A = group 2p, B = group 2p+1) with the
// SAME resident weights. Schedule per loop (one step of A and B):
//   issue pollA | ph1_A | issue pollB | ph1_B | check A | bar |
//   ph2_A, update_A | check B | bar | ph2_B, update_B | publish A,B | bar
// Every MALL RTT (publish visibility + poll return) is covered by the other
// stream's MFMA/update work; publishes sit after the last vmcnt(0) check so
// checks never wait on store-acks (consumption is a full loop later, so the
// pair slack is ample).
// Exchange protocol: R0-proven parity-tagged agent-scope (MALL) atomics,
// upgraded to 2-bit mantissa tags {1,3}: harness poison 0xAA.. has low bits
// 10b and the pre-h0 visibility-reorder window can never false-accept.
// Tag bits live below bf16 rounding (~2^-15 tie-flip risk only).
// Bounded poll guards: any visibility bug -> absmax fail, never a hang.
// ---------------------------------------------------------------------------
__global__ __launch_bounds__(512, 2) void lstm_kernel(
    const float* __restrict__ x, const float* __restrict__ h0,
    const float* __restrict__ c0, const float* __restrict__ W_ih,
    const float* __restrict__ W_hh, const float* __restrict__ b_ih,
    const float* __restrict__ b_hh, float* __restrict__ exch,
    uint16_t* __restrict__ hs) {
  const int tid   = threadIdx.x;
  const int blk   = blockIdx.x;
  const int p     = blk & 15;
  const int half  = blk >> 4;
  const int partner = blk ^ 16;
  const int b0A   = (2 * p) * 16;
  const int b0B   = (2 * p + 1) * 16;
  const int w     = tid >> 6;
  const int lane  = tid & 63;
  const int quad  = lane >> 4;
  const int l16   = lane & 15;
  const int w16l  = w * 16 + l16;          // hh within half, 0..127

  __shared__ short AldsA[16 * 328];        // [h(256) | x(64)] bf16, stream A
  __shared__ short AldsB[16 * 328];        // stream B

  const int urow = tid >> 5;
  const int hh0  = (tid & 31) * 4;
  const int xc   = (tid & 31) * 2;

  // exchange: per block 4 buffers (stream s, parity b) x 1024 u64 = 32 KB.
  const int widx = tid * 2;
  unsigned long long* const sb_base =
      (unsigned long long*)exch + (size_t)blk * 4096 + widx;
  const unsigned long long* const pb_base =
      (const unsigned long long*)exch + (size_t)partner * 4096 + widx;

  // ---- resident weights, gate-major cols, PERMUTED by half (as R4):
  // bw[0..3] = own-half h K-tiles, bw[4..7] = partner-half, bw[8..9] = x.
  short8 bw[10][4];
#pragma unroll
  for (int j = 0; j < 10; ++j) {
    int ktA = (j < 4) ? (half * 4 + j) : (j < 8) ? ((1 - half) * 4 + (j - 4)) : j;
#pragma unroll
    for (int g = 0; g < 4; ++g) {
      int grow = g * 256 + half * 128 + w16l;      // output row in 4H
      const float* src = (ktA < 8)
          ? (W_hh + (size_t)grow * 256 + ktA * 32 + quad * 8)
          : (W_ih + (size_t)grow * 64 + (ktA - 8) * 32 + quad * 8);
      short8 bv;
#pragma unroll
      for (int e = 0; e < 8; ++e) bv[e] = f2bf(src[e]);
      bw[j][g] = bv;
    }
  }

  const int hh_abs = half * 128 + w16l;
  float bias_g[4];
#pragma unroll
  for (int g = 0; g < 4; ++g)
    bias_g[g] = b_ih[g * 256 + hh_abs] + b_hh[g * 256 + hh_abs];
  float cA[4], cB[4];
#pragma unroll
  for (int r = 0; r < 4; ++r) {
    cA[r] = c0[(size_t)(b0A + quad * 4 + r) * 256 + hh_abs];
    cB[r] = c0[(size_t)(b0B + quad * 4 + r) * 256 + hh_abs];
  }

  // ---- init A-LDS: full h0 + x(0), both streams
  {
    int c8 = (tid & 31) * 8;
    short8 hv;
    const float* hpA = h0 + (size_t)(b0A + urow) * 256 + c8;
#pragma unroll
    for (int e = 0; e < 8; ++e) hv[e] = f2bf(hpA[e]);
    *(short8*)&AldsA[urow * 328 + c8] = hv;
    const float* hpB = h0 + (size_t)(b0B + urow) * 256 + c8;
#pragma unroll
    for (int e = 0; e < 8; ++e) hv[e] = f2bf(hpB[e]);
    *(short8*)&AldsB[urow * 328 + c8] = hv;
    const float* xpA = x + ((size_t)(b0A + urow) * T_STEPS + 0) * DIN + xc;
    short2v xv; xv[0] = f2bf(xpA[0]); xv[1] = f2bf(xpA[1]);
    *(short2v*)&AldsA[urow * 328 + 256 + xc] = xv;
    const float* xpB = x + ((size_t)(b0B + urow) * T_STEPS + 0) * DIN + xc;
    xv[0] = f2bf(xpB[0]); xv[1] = f2bf(xpB[1]);
    *(short2v*)&AldsB[urow * 328 + 256 + xc] = xv;
  }
  __syncthreads();

  const int ownbase = half * 128;
  const int pbase   = (1 - half) * 128;

#define PH1(AL, ACC)                                                          \
  _Pragma("unroll")                                                           \
  for (int j = 0; j < 4; ++j) {                                               \
    short8 a = *(const short8*)&AL[l16 * 328 + ownbase + j * 32 + quad * 8];  \
    _Pragma("unroll")                                                         \
    for (int g = 0; g < 4; ++g)                                               \
      ACC[g] = __builtin_amdgcn_mfma_f32_16x16x32_bf16(a, bw[j][g], ACC[g], 0, 0, 0); \
  }                                                                           \
  _Pragma("unroll")                                                           \
  for (int j = 8; j < 10; ++j) {                                              \
    short8 a = *(const short8*)&AL[l16 * 328 + 256 + (j - 8) * 32 + quad * 8];\
    _Pragma("unroll")                                                         \
    for (int g = 0; g < 4; ++g)                                               \
      ACC[g] = __builtin_amdgcn_mfma_f32_16x16x32_bf16(a, bw[j][g], ACC[g], 0, 0, 0); \
  }

#define PH2(AL, ACC)                                                          \
  _Pragma("unroll")                                                           \
  for (int j = 4; j < 8; ++j) {                                               \
    short8 a = *(const short8*)&AL[l16 * 328 + pbase + (j - 4) * 32 + quad * 8]; \
    _Pragma("unroll")                                                         \
    for (int g = 0; g < 4; ++g)                                               \
      ACC[g] = __builtin_amdgcn_mfma_f32_16x16x32_bf16(a, bw[j][g], ACC[g], 0, 0, 0); \
  }

#define CHECK_POLL(PB, R0, R1, PV)                                            \
  do {                                                                        \
    unsigned tag2 = (((unsigned)(t - 1) >> 1) & 1u) ? 3u : 1u;                \
    int guard = 0;                                                            \
    for (;;) {                                                                \
      bool ok = ((((unsigned)R0) & 3u) == tag2) &                             \
                ((((unsigned)(R0 >> 32)) & 3u) == tag2) &                     \
                ((((unsigned)R1) & 3u) == tag2) &                             \
                ((((unsigned)(R1 >> 32)) & 3u) == tag2);                      \
      if (ok) break;                                                          \
      if (++guard > 4096) break;                                              \
      __builtin_amdgcn_s_sleep(1);                                            \
      apoll_issue(PB, R0, R1);                                                \
      apoll_wait(R0, R1);                                                     \
    }                                                                         \
    union { unsigned u; float f; } q0, q1, q2, q3;                            \
    q0.u = (unsigned)R0; q1.u = (unsigned)(R0 >> 32);                         \
    q2.u = (unsigned)R1; q3.u = (unsigned)(R1 >> 32);                         \
    PV[0] = f2bf(q0.f); PV[1] = f2bf(q1.f);                                   \
    PV[2] = f2bf(q2.f); PV[3] = f2bf(q3.f);                                   \
  } while (0)

#define UPD(ACC, CREG, HF, HB)                                                \
  _Pragma("unroll")                                                           \
  for (int r = 0; r < 4; ++r) {                                               \
    float iv = sigm(ACC[0][r] + bias_g[0]);                                   \
    float fv = sigm(ACC[1][r] + bias_g[1]);                                   \
    float gv = tanh_f(ACC[2][r] + bias_g[2]);                                 \
    float ov = sigm(ACC[3][r] + bias_g[3]);                                   \
    float cv = fv * CREG[r] + iv * gv;                                        \
    CREG[r] = cv;                                                             \
    HF[r] = ov * tanh_f(cv);                                                  \
    HB[r] = f2bf(HF[r]);                                                      \
  }

#define PUB(SB, HF)                                                           \
  do {                                                                        \
    unsigned tag2 = (((unsigned)t >> 1) & 1u) ? 3u : 1u;                      \
    union { float f; unsigned u; } u0, u1, u2, u3;                            \
    u0.f = HF[0]; u1.f = HF[1]; u2.f = HF[2]; u3.f = HF[3];                   \
    unsigned long long w0 = (unsigned long long)((u0.u & ~3u) | tag2)         \
                          | ((unsigned long long)((u1.u & ~3u) | tag2) << 32);\
    unsigned long long w1 = (unsigned long long)((u2.u & ~3u) | tag2)         \
                          | ((unsigned long long)((u3.u & ~3u) | tag2) << 32);\
    __hip_atomic_store(SB,     w0, __ATOMIC_RELAXED, __HIP_MEMORY_SCOPE_AGENT); \
    __hip_atomic_store(SB + 1, w1, __ATOMIC_RELAXED, __HIP_MEMORY_SCOPE_AGENT); \
  } while (0)

  for (int t = 0; t < T_STEPS; ++t) {
    const unsigned long long* pbA = pb_base + (size_t)(((t - 1) & 1)) * 1024;
    const unsigned long long* pbB = pb_base + (size_t)(2 + ((t - 1) & 1)) * 1024;
    unsigned long long* sbA = sb_base + (size_t)(t & 1) * 1024;
    unsigned long long* sbB = sb_base + (size_t)(2 + (t & 1)) * 1024;

    unsigned long long rA0 = 0, rA1 = 0, rB0 = 0, rB1 = 0;
    float4v accA[4] = {{0.f,0.f,0.f,0.f},{0.f,0.f,0.f,0.f},
                       {0.f,0.f,0.f,0.f},{0.f,0.f,0.f,0.f}};
    float4v accB[4] = {{0.f,0.f,0.f,0.f},{0.f,0.f,0.f,0.f},
                       {0.f,0.f,0.f,0.f},{0.f,0.f,0.f,0.f}};

    if (t > 0) apoll_issue(pbA, rA0, rA1);   // A poll in flight under ph1s

    int tn = (t + 1 < T_STEPS) ? (t + 1) : t;
    const float* xpA = x + ((size_t)(b0A + urow) * T_STEPS + tn) * DIN + xc;
    float xa0 = xpA[0], xa1 = xpA[1];

    PH1(AldsA, accA);

    if (t > 0) apoll_issue(pbB, rB0, rB1);   // B poll in flight

    const float* xpB = x + ((size_t)(b0B + urow) * T_STEPS + tn) * DIN + xc;
    float xb0 = xpB[0], xb1 = xpB[1];

    PH1(AldsB, accB);

    // deferred hs values: read h(t-1) rows from LDS now, store late
    short4v hvA, hvB;
    if (t > 0) {
      hvA = *(const short4v*)&AldsA[urow * 328 + ownbase + hh0];
      hvB = *(const short4v*)&AldsB[urow * 328 + ownbase + hh0];
    }

    if (t > 0) {
      apoll_wait(rA0, rA1);
      short4v pvA;
      CHECK_POLL(pbA, rA0, rA1, pvA);
#pragma unroll
      for (int r = 0; r < 4; ++r)
        AldsA[(quad * 4 + r) * 328 + pbase + w16l] = pvA[r];
    }
    __syncthreads();   // bar1: AldsA partner region ready

    PH2(AldsA, accA);
    float hfA[4]; short hbA[4];
    UPD(accA, cA, hfA, hbA);
#pragma unroll
    for (int r = 0; r < 4; ++r)
      AldsA[(quad * 4 + r) * 328 + ownbase + w16l] = hbA[r];
    {
      short2v xv; xv[0] = f2bf(xa0); xv[1] = f2bf(xa1);
      *(short2v*)&AldsA[urow * 328 + 256 + xc] = xv;
    }

    if (t > 0) {
      apoll_wait(rB0, rB1);
      short4v pvB;
      CHECK_POLL(pbB, rB0, rB1, pvB);
#pragma unroll
      for (int r = 0; r < 4; ++r)
        AldsB[(quad * 4 + r) * 328 + pbase + w16l] = pvB[r];
    }
    __syncthreads();   // bar2: AldsB partner ready; AldsA own+x writes done

    PH2(AldsB, accB);
    float hfB[4]; short hbB[4];
    UPD(accB, cB, hfB, hbB);
#pragma unroll
    for (int r = 0; r < 4; ++r)
      AldsB[(quad * 4 + r) * 328 + ownbase + w16l] = hbB[r];
    {
      short2v xv; xv[0] = f2bf(xb0); xv[1] = f2bf(xb1);
      *(short2v*)&AldsB[urow * 328 + 256 + xc] = xv;
    }

    // publishes LAST (after all vmcnt(0) checks) -- consumption is a full
    // loop away, so the pair slack absorbs the later issue.
    PUB(sbA, hfA);
    PUB(sbB, hfB);

    // deferred hs global stores (coalesced row-major)
    if (t > 0) {
      *(short4v*)(hs + ((size_t)(b0A + urow) * T_STEPS + (t - 1)) * HID + ownbase + hh0) = hvA;
      *(short4v*)(hs + ((size_t)(b0B + urow) * T_STEPS + (t - 1)) * HID + ownbase + hh0) = hvB;
    }
    __syncthreads();   // bar3: AldsB own+x ready for next loop
  }

  // ---- epilogue: hs for the final step
  {
    short4v hvA = *(const short4v*)&AldsA[urow * 328 + ownbase + hh0];
    *(short4v*)(hs + ((size_t)(b0A + urow) * T_STEPS + (T_STEPS - 1)) * HID + ownbase + hh0) = hvA;
    short4v hvB = *(const short4v*)&AldsB[urow * 328 + ownbase + hh0];
    *(short4v*)(hs + ((size_t)(b0B + urow) * T_STEPS + (T_STEPS - 1)) * HID + ownbase + hh0) = hvB;
  }
#undef PH1
#undef PH2
#undef CHECK_POLL
#undef UPD
#undef PUB
}

// ---------------------------------------------------------------------------
// One-time fp32 -> bf16 conversion of MLP weights into workspace.
// ---------------------------------------------------------------------------
__global__ void prep_kernel(const float* __restrict__ W1, const float* __restrict__ W2,
                            short* __restrict__ W1b, short* __restrict__ W2b) {
  int i = blockIdx.x * 512 + threadIdx.x;   // 160*512 = 81920 = 65536 + 16384
  if (i < 65536) W1b[i] = f2bf(W1[i]);
  else           W2b[i - 65536] = f2bf(W2[i - 65536]);
}

// ---------------------------------------------------------------------------
// Fused MLP head: y = relu(hs @ W1^T + b1) @ W2^T + b2, * mask.
// 4096 blocks x 128 rows (unchanged).
// ---------------------------------------------------------------------------
__global__ __launch_bounds__(512, 2) void mlp_kernel(
    const uint16_t* __restrict__ hs, const short* __restrict__ W1b,
    const float* __restrict__ b1, const short* __restrict__ W2b,
    const float* __restrict__ b2, const float* __restrict__ mask,
    float* __restrict__ y) {
  const int tid   = threadIdx.x;
  const int rows0 = blockIdx.x * 128;
  const int w     = tid >> 6;
  const int lane  = tid & 63;
  const int quad  = lane >> 4;
  const int l16   = lane & 15;

  __shared__ short S[128 * 264];  // h tile, later aliased as act tile

  // stage h tile [128,256] bf16
#pragma unroll
  for (int kk = 0; kk < 8; ++kk) {
    int c   = tid + kk * 512;
    int row = c >> 5;
    int off = (c & 31) * 8;
    *(short8*)&S[row * 264 + off] =
        *(const short8*)(hs + (size_t)(rows0 + row) * HID + off);
  }

  // W1 B-fragments; wave w owns hidden cols [w*32, w*32+32)
  short8 bf1[2][8];
  float  b1v[2];
#pragma unroll
  for (int nt = 0; nt < 2; ++nt) {
    int n = w * 32 + nt * 16 + l16;
    b1v[nt] = b1[n];
#pragma unroll
    for (int kt = 0; kt < 8; ++kt)
      bf1[nt][kt] = *(const short8*)(W1b + (size_t)n * 256 + kt * 32 + quad * 8);
  }
  __syncthreads();

  // GEMM1: act = relu(h @ W1^T + b1), 8 M-tiles
  float4v acc1[2][8];
#pragma unroll
  for (int nt = 0; nt < 2; ++nt)
#pragma unroll
    for (int mt = 0; mt < 8; ++mt) acc1[nt][mt] = (float4v){0.f,0.f,0.f,0.f};
#pragma unroll
  for (int kt = 0; kt < 8; ++kt) {
#pragma unroll
    for (int mt = 0; mt < 8; ++mt) {
      short8 a = *(const short8*)&S[(mt * 16 + l16) * 264 + kt * 32 + quad * 8];
#pragma unroll
      for (int nt = 0; nt < 2; ++nt)
        acc1[nt][mt] = __builtin_amdgcn_mfma_f32_16x16x32_bf16(a, bf1[nt][kt], acc1[nt][mt], 0, 0, 0);
    }
  }
  __syncthreads();  // all h reads done before aliasing S as act

#pragma unroll
  for (int nt = 0; nt < 2; ++nt) {
    int col = w * 32 + nt * 16 + l16;
#pragma unroll
    for (int mt = 0; mt < 8; ++mt)
#pragma unroll
      for (int r = 0; r < 4; ++r) {
        float v = acc1[nt][mt][r] + b1v[nt];
        v = v > 0.f ? v : 0.f;
        S[(mt * 16 + quad * 4 + r) * 264 + col] = f2bf(v);
      }
  }
  __syncthreads();

  // GEMM2: D = W2 * act^T ; wave w: out-ch tile mt2=w>>1, row half (w&1)
  const int mt2 = w >> 1;
  short8 a2[8];
#pragma unroll
  for (int kt = 0; kt < 8; ++kt)
    a2[kt] = *(const short8*)(W2b + (size_t)(mt2 * 16 + l16) * 256 + kt * 32 + quad * 8);
  float4v acc2[4] = {{0.f,0.f,0.f,0.f},{0.f,0.f,0.f,0.f},
                     {0.f,0.f,0.f,0.f},{0.f,0.f,0.f,0.f}};
#pragma unroll
  for (int kt = 0; kt < 8; ++kt) {
#pragma unroll
    for (int nt2 = 0; nt2 < 4; ++nt2) {
      int n0 = (w & 1) * 64 + nt2 * 16;
      short8 b = *(const short8*)&S[(n0 + l16) * 264 + kt * 32 + quad * 8];
      acc2[nt2] = __builtin_amdgcn_mfma_f32_16x16x32_bf16(a2[kt], b, acc2[nt2], 0, 0, 0);
    }
  }
  const float* b2p = b2 + mt2 * 16 + quad * 4;
  float b2v0 = b2p[0], b2v1 = b2p[1], b2v2 = b2p[2], b2v3 = b2p[3];
#pragma unroll
  for (int nt2 = 0; nt2 < 4; ++nt2) {
    int R = rows0 + (w & 1) * 64 + nt2 * 16 + l16;
    float m = mask[R];
    float4v out;
    out[0] = (acc2[nt2][0] + b2v0) * m;
    out[1] = (acc2[nt2][1] + b2v1) * m;
    out[2] = (acc2[nt2][2] + b2v2) * m;
    out[3] = (acc2[nt2][3] + b2v3) * m;
    *(float4v*)(y + (size_t)R * 64 + mt2 * 16 + quad * 4) = out;
  }
}

extern "C" void kernel_launch(void* const* d_in, const int* in_sizes, int n_in,
                              void* d_out, int out_size, void* d_ws, size_t ws_size,
                              hipStream_t stream) {
  (void)in_sizes; (void)n_in; (void)out_size; (void)ws_size;
  const float* x    = (const float*)d_in[0];
  const float* mask = (const float*)d_in[1];
  const float* h0   = (const float*)d_in[2];
  const float* c0   = (const float*)d_in[3];
  const float* W_ih = (const float*)d_in[4];
  const float* W_hh = (const float*)d_in[5];
  const float* b_ih = (const float*)d_in[6];
  const float* b_hh = (const float*)d_in[7];
  const float* W1   = (const float*)d_in[8];
  const float* b1   = (const float*)d_in[9];
  const float* W2   = (const float*)d_in[10];
  const float* b2   = (const float*)d_in[11];
  float* y = (float*)d_out;

  char* ws = (char*)d_ws;
  float*    exch = (float*)ws;                           // 1 MiB MALL exchange (32 blk x 4 buf x 8KB), 2-bit-tagged
  short*    W1b  = (short*)(ws + (1u << 20));            // 128 KiB
  short*    W2b  = (short*)(ws + (1u << 20) + 131072);   // 32 KiB
  uint16_t* hs   = (uint16_t*)(ws + (2u << 20));         // [B,T,H] bf16 = 256 MiB

  prep_kernel<<<160, 512, 0, stream>>>(W1, W2, W1b, W2b);
  lstm_kernel<<<32, 512, 0, stream>>>(x, h0, c0, W_ih, W_hh, b_ih, b_hh, exch, hs);
  mlp_kernel<<<4096, 512, 0, stream>>>(hs, W1b, b1, W2b, b2, mask, y);
}